// Round 10
// baseline (246.482 us; speedup 1.0000x reference)
//
#include <hip/hip_runtime.h>

typedef float f32x4 __attribute__((ext_vector_type(4)));
typedef short short8 __attribute__((ext_vector_type(8)));
typedef unsigned short ushort8 __attribute__((ext_vector_type(8)));

// ---------------- workspace layout (ushort elements) ----------------
// WTt (3 x [64 ks][128 h][32 c] bf16): 0 .. 786432
// Q  ([8*2048][128] bf16):        786432
// K  ([8*2048][128] bf16):        2883584
// Vt ([8][128][2048] bf16):       4980736
#define WS_Q  786432
#define WS_K  2883584
#define WS_VT 4980736

__device__ __forceinline__ unsigned short f2bf(float x) {
    unsigned u = __float_as_uint(x);
    u += 0x7FFFu + ((u >> 16) & 1u);      // RNE
    return (unsigned short)(u >> 16);
}

__device__ __forceinline__ short8 cvt8(float4 lo, float4 hi) {
    union { unsigned u[4]; short8 s; } r;
    asm("v_cvt_pk_bf16_f32 %0, %1, %2" : "=v"(r.u[0]) : "v"(lo.x), "v"(lo.y));
    asm("v_cvt_pk_bf16_f32 %0, %1, %2" : "=v"(r.u[1]) : "v"(lo.z), "v"(lo.w));
    asm("v_cvt_pk_bf16_f32 %0, %1, %2" : "=v"(r.u[2]) : "v"(hi.x), "v"(hi.y));
    asm("v_cvt_pk_bf16_f32 %0, %1, %2" : "=v"(r.u[3]) : "v"(hi.z), "v"(hi.w));
    return r.s;
}

// swizzle for 128-byte rows (attn P buffer)
__device__ __forceinline__ int swz128(int row, int cbyte) {
    return row * 128 + (cbyte ^ ((row & 7) << 4));
}

// ================= K0: W [2048][128] fp32 -> WTt [64 ks][128 h][32 c] bf16
__global__ __launch_bounds__(256) void wt_kernel(const float* __restrict__ Wq,
        const float* __restrict__ Wk, const float* __restrict__ Wv,
        unsigned short* __restrict__ ws) {
    __shared__ __align__(16) unsigned short tile[64][136];
    int mat = blockIdx.x >> 5, ct = blockIdx.x & 31;
    const float* W = (mat == 0) ? Wq : ((mat == 1) ? Wk : Wv);
    int cbase = ct * 64;
    int tid = threadIdx.x;
#pragma unroll
    for (int p = 0; p < 8; p++) {
        int fidx = p * 256 + tid;          // float4 index, 2048 total
        int row = fidx >> 5;               // c within tile (0..63)
        int c4 = (fidx & 31) << 2;         // h (0..124)
        float4 v = *(const float4*)&W[(size_t)(cbase + row) * 128 + c4];
        tile[row][c4 + 0] = f2bf(v.x);
        tile[row][c4 + 1] = f2bf(v.y);
        tile[row][c4 + 2] = f2bf(v.z);
        tile[row][c4 + 3] = f2bf(v.w);
    }
    __syncthreads();
    int h = tid >> 1, seg = tid & 1;
    unsigned short* dst = ws + mat * 262144 + (ct * 2 + seg) * 4096 + h * 32;
#pragma unroll
    for (int q4 = 0; q4 < 4; q4++) {
        ushort8 pk;
#pragma unroll
        for (int e = 0; e < 8; e++) pk[e] = tile[seg * 32 + q4 * 8 + e][h];
        *(ushort8*)(dst + q4 * 8) = pk;
    }
}

// ================= K1: QKV projection, 128x128 tile, depth-3 pipeline =====
// Block = one matrix x one 128-row x-strip (grid 384). BK=32, 64 K-steps.
// 4 waves, each owns a 64x64 quadrant (4x4 frags, 16 MFMA/step).
// 3 LDS buffers of 16KB (A bf16 8KB | B bf16 8KB) -> 3 blocks/CU.
// Per-thread VMEM group = 6 ops (4 A float4 + 2 B global_load_lds);
// body T issues group T+2, waits vmcnt(6) => group T+1 landed.
__global__ __launch_bounds__(256, 3) void qkv_kernel(const float* __restrict__ x,
        const float* __restrict__ bq, const float* __restrict__ bk,
        const float* __restrict__ bv, unsigned short* __restrict__ ws) {
    __shared__ __align__(16) char lds_raw[3][16384];   // 48 KB
    int bid = blockIdx.x;
    int matrix = bid >> 7;              // 0=Q 1=K 2=V
    int strip = bid & 127;              // 128-row strip of x
    const unsigned short* WTt = ws + matrix * 262144;
    const float* x0 = x + (size_t)strip * 128 * 2048;
    int tid = threadIdx.x, lane = tid & 63, wid = tid >> 6;
    int lr = lane & 15, lg = lane >> 4;
    int m0 = (wid >> 1) * 64, n0 = (wid & 1) * 64;

    // bias loads drained before the pipeline so vmcnt counts stay exact
    const float* bias = (matrix == 0) ? bq : ((matrix == 1) ? bk : bv);
    float bb[4];
#pragma unroll
    for (int j2 = 0; j2 < 4; j2++) bb[j2] = bias[n0 + j2 * 16 + lr];
    asm volatile("" : "+v"(bb[0]), "+v"(bb[1]), "+v"(bb[2]), "+v"(bb[3]));
    asm volatile("s_waitcnt vmcnt(0)" ::: "memory");

    // A staging: thread owns 16 floats (half of one 32-float row)
    int rowA = tid >> 1, hf = tid & 1;
    const float* aSrc = x0 + (size_t)rowA * 2048 + hf * 16;
    int aDst0 = rowA * 64 + (((hf * 2 + 0) ^ ((rowA >> 1) & 3)) << 4);
    int aDst1 = rowA * 64 + (((hf * 2 + 1) ^ ((rowA >> 1) & 3)) << 4);

    // B staging (DMA): 2 x 1KB chunks per wave, pre-swizzled global source
    int bsrc0, bsrc1, bdst0, bdst1;
    {
        int sig0 = wid * 64 + lane;
        int r0 = sig0 >> 2, s0 = (sig0 & 3) ^ ((r0 >> 1) & 3);
        bsrc0 = r0 * 32 + s0 * 8;  bdst0 = wid * 1024;
        int sig1 = (4 + wid) * 64 + lane;
        int r1 = sig1 >> 2, s1 = (sig1 & 3) ^ ((r1 >> 1) & 3);
        bsrc1 = r1 * 32 + s1 * 8;  bdst1 = (4 + wid) * 1024;
    }

    // fragment read offsets (bytes, swizzled). B region at +8192.
    int aOff0, aOff1, aOff2, aOff3, bOff0, bOff1, bOff2, bOff3;
    {
        int r0 = m0 + 0 * 16 + lr; aOff0 = r0 * 64 + ((lg ^ ((r0 >> 1) & 3)) << 4);
        int r1 = m0 + 1 * 16 + lr; aOff1 = r1 * 64 + ((lg ^ ((r1 >> 1) & 3)) << 4);
        int r2 = m0 + 2 * 16 + lr; aOff2 = r2 * 64 + ((lg ^ ((r2 >> 1) & 3)) << 4);
        int r3 = m0 + 3 * 16 + lr; aOff3 = r3 * 64 + ((lg ^ ((r3 >> 1) & 3)) << 4);
        int h0 = n0 + 0 * 16 + lr; bOff0 = 8192 + h0 * 64 + ((lg ^ ((h0 >> 1) & 3)) << 4);
        int h1 = n0 + 1 * 16 + lr; bOff1 = 8192 + h1 * 64 + ((lg ^ ((h1 >> 1) & 3)) << 4);
        int h2 = n0 + 2 * 16 + lr; bOff2 = 8192 + h2 * 64 + ((lg ^ ((h2 >> 1) & 3)) << 4);
        int h3 = n0 + 3 * 16 + lr; bOff3 = 8192 + h3 * 64 + ((lg ^ ((h3 >> 1) & 3)) << 4);
    }

    f32x4 acc[4][4];
#pragma unroll
    for (int i = 0; i < 4; i++)
#pragma unroll
        for (int j3 = 0; j3 < 4; j3++) acc[i][j3] = (f32x4){0.f, 0.f, 0.f, 0.f};
    float4 rA[2][4];   // ping-pong in-flight A slots (16 floats each)

#define ISSUE_A(SLOT, T) do { \
        const float* ap_ = aSrc + (size_t)(T) * 32; \
        rA[SLOT][0] = *(const float4*)ap_; \
        rA[SLOT][1] = *(const float4*)(ap_ + 4); \
        rA[SLOT][2] = *(const float4*)(ap_ + 8); \
        rA[SLOT][3] = *(const float4*)(ap_ + 12); \
    } while (0)
#define ISSUE_B(BUF, T) do { \
        const unsigned short* bs_ = WTt + (size_t)(T) * 4096; \
        char* bd_ = &lds_raw[BUF][8192]; \
        __builtin_amdgcn_global_load_lds((const __attribute__((address_space(1))) unsigned*)(bs_ + bsrc0), \
            (__attribute__((address_space(3))) unsigned*)(bd_ + bdst0), 16, 0, 0); \
        __builtin_amdgcn_global_load_lds((const __attribute__((address_space(1))) unsigned*)(bs_ + bsrc1), \
            (__attribute__((address_space(3))) unsigned*)(bd_ + bdst1), 16, 0, 0); \
    } while (0)
#define WRITE_A(SLOT, BUF) do { \
        short8 p0_ = cvt8(rA[SLOT][0], rA[SLOT][1]); \
        short8 p1_ = cvt8(rA[SLOT][2], rA[SLOT][3]); \
        *(short8*)(&lds_raw[BUF][0] + aDst0) = p0_; \
        *(short8*)(&lds_raw[BUF][0] + aDst1) = p1_; \
    } while (0)

    // body(T): frags(T) | issue grp(T+2) | 16 MFMA | wait | write A(T+1) | bar
#define QKV_BODY(U, T, STAGE, WAIT0, WRITE, BAR) do { \
        const char* Lb_ = &lds_raw[U][0]; \
        short8 av0 = *(const short8*)(Lb_ + aOff0); \
        short8 av1 = *(const short8*)(Lb_ + aOff1); \
        short8 av2 = *(const short8*)(Lb_ + aOff2); \
        short8 av3 = *(const short8*)(Lb_ + aOff3); \
        short8 bv0 = *(const short8*)(Lb_ + bOff0); \
        short8 bv1 = *(const short8*)(Lb_ + bOff1); \
        short8 bv2 = *(const short8*)(Lb_ + bOff2); \
        short8 bv3 = *(const short8*)(Lb_ + bOff3); \
        if (STAGE) { ISSUE_A((T) & 1, (T) + 2); ISSUE_B(((U) + 2) % 3, (T) + 2); } \
        acc[0][0] = __builtin_amdgcn_mfma_f32_16x16x32_bf16(av0, bv0, acc[0][0], 0, 0, 0); \
        acc[0][1] = __builtin_amdgcn_mfma_f32_16x16x32_bf16(av0, bv1, acc[0][1], 0, 0, 0); \
        acc[0][2] = __builtin_amdgcn_mfma_f32_16x16x32_bf16(av0, bv2, acc[0][2], 0, 0, 0); \
        acc[0][3] = __builtin_amdgcn_mfma_f32_16x16x32_bf16(av0, bv3, acc[0][3], 0, 0, 0); \
        acc[1][0] = __builtin_amdgcn_mfma_f32_16x16x32_bf16(av1, bv0, acc[1][0], 0, 0, 0); \
        acc[1][1] = __builtin_amdgcn_mfma_f32_16x16x32_bf16(av1, bv1, acc[1][1], 0, 0, 0); \
        acc[1][2] = __builtin_amdgcn_mfma_f32_16x16x32_bf16(av1, bv2, acc[1][2], 0, 0, 0); \
        acc[1][3] = __builtin_amdgcn_mfma_f32_16x16x32_bf16(av1, bv3, acc[1][3], 0, 0, 0); \
        acc[2][0] = __builtin_amdgcn_mfma_f32_16x16x32_bf16(av2, bv0, acc[2][0], 0, 0, 0); \
        acc[2][1] = __builtin_amdgcn_mfma_f32_16x16x32_bf16(av2, bv1, acc[2][1], 0, 0, 0); \
        acc[2][2] = __builtin_amdgcn_mfma_f32_16x16x32_bf16(av2, bv2, acc[2][2], 0, 0, 0); \
        acc[2][3] = __builtin_amdgcn_mfma_f32_16x16x32_bf16(av2, bv3, acc[2][3], 0, 0, 0); \
        acc[3][0] = __builtin_amdgcn_mfma_f32_16x16x32_bf16(av3, bv0, acc[3][0], 0, 0, 0); \
        acc[3][1] = __builtin_amdgcn_mfma_f32_16x16x32_bf16(av3, bv1, acc[3][1], 0, 0, 0); \
        acc[3][2] = __builtin_amdgcn_mfma_f32_16x16x32_bf16(av3, bv2, acc[3][2], 0, 0, 0); \
        acc[3][3] = __builtin_amdgcn_mfma_f32_16x16x32_bf16(av3, bv3, acc[3][3], 0, 0, 0); \
        if (STAGE)      { asm volatile("s_waitcnt vmcnt(6)" ::: "memory"); } \
        else if (WAIT0) { asm volatile("s_waitcnt vmcnt(0)" ::: "memory"); } \
        if (WRITE) { \
            WRITE_A(((T) + 1) & 1, ((U) + 1) % 3); \
            asm volatile("s_waitcnt lgkmcnt(0)" ::: "memory"); \
        } \
        if (BAR) __builtin_amdgcn_s_barrier(); \
    } while (0)

    // prologue: groups 0,1 in flight; tile 0's A written
    ISSUE_A(0, 0); ISSUE_B(0, 0);
    ISSUE_A(1, 1); ISSUE_B(1, 1);
    asm volatile("s_waitcnt vmcnt(6)" ::: "memory");   // group 0 landed
    WRITE_A(0, 0);
    asm volatile("s_waitcnt lgkmcnt(0)" ::: "memory");
    __builtin_amdgcn_s_barrier();

    for (int to = 0; to < 20; to++) {
        int T0 = to * 3;
        QKV_BODY(0, T0 + 0, true, false, true, true);
        QKV_BODY(1, T0 + 1, true, false, true, true);
        QKV_BODY(2, T0 + 2, true, false, true, true);
    }
    QKV_BODY(0, 60, true,  false, true,  true);   // issues grp 62
    QKV_BODY(1, 61, true,  false, true,  true);   // issues grp 63; 62 landed
    QKV_BODY(2, 62, false, true,  true,  true);   // grp 63 landed
    QKV_BODY(0, 63, false, false, false, false);

    // ----- epilogue -----
    if (matrix < 2) {
        unsigned short* outp = ws + ((matrix == 0) ? WS_Q : WS_K);
        float sc = (matrix == 0) ? 0.08838834764831845f : 1.0f;   // H^-0.5 in Q
#pragma unroll
        for (int i = 0; i < 4; i++)
#pragma unroll
            for (int j3 = 0; j3 < 4; j3++) {
                int h = n0 + j3 * 16 + lr;
#pragma unroll
                for (int r = 0; r < 4; r++) {
                    size_t t = (size_t)strip * 128 + m0 + i * 16 + (lg << 2) + r;
                    outp[t * 128 + h] = f2bf((acc[i][j3][r] + bb[j3]) * sc);
                }
            }
    } else {
        __syncthreads();   // all frag reads done before LDS reuse
        unsigned short* sm = (unsigned short*)&lds_raw[0][0];   // [128][136]
#pragma unroll
        for (int i = 0; i < 4; i++)
#pragma unroll
            for (int j3 = 0; j3 < 4; j3++) {
                int h = n0 + j3 * 16 + lr;
#pragma unroll
                for (int r = 0; r < 4; r++) {
                    int tl = m0 + i * 16 + (lg << 2) + r;
                    sm[tl * 136 + h] = f2bf(acc[i][j3][r] + bb[j3]);
                }
            }
        __syncthreads();
        int h2 = tid >> 1, seg = tid & 1;
        int batch = strip >> 4;
        int tin = (strip & 15) * 128 + seg * 64;
        unsigned short* vt = ws + WS_VT + ((size_t)batch * 128 + h2) * 2048 + tin;
#pragma unroll
        for (int q8 = 0; q8 < 8; q8++) {
            ushort8 pk;
#pragma unroll
            for (int e = 0; e < 8; e++) pk[e] = sm[(seg * 64 + q8 * 8 + e) * 136 + h2];
            *(ushort8*)(vt + q8 * 8) = pk;
        }
    }
#undef QKV_BODY
#undef WRITE_A
#undef ISSUE_B
#undef ISSUE_A
}

// ================= K2: causal flash attention (unchanged) =================
__global__ __launch_bounds__(256, 2) void attn_kernel(const unsigned short* __restrict__ ws,
        float* __restrict__ out) {
    __shared__ __align__(16) float o_lds[4][32][128];   // 64 KB
    __shared__ float ml[4][2][32];
    int b = blockIdx.x;
    int qi = 63 - (int)blockIdx.y;          // longest blocks first
    int qbase = qi * 32;
    int tid = threadIdx.x, lane = tid & 63, w = tid >> 6;
    int lr = lane & 15, lg = lane >> 4;
    const unsigned short* Qb = ws + WS_Q + (size_t)b * 2048 * 128;
    const unsigned short* Kb = ws + WS_K + (size_t)b * 2048 * 128;
    const unsigned short* Vt = ws + WS_VT + (size_t)b * 128 * 2048;
    char* p_lds = (char*)&o_lds[w][0][0];   // per-wave private 4 KB

    short8 qf[2][4];
#pragma unroll
    for (int i = 0; i < 2; i++)
#pragma unroll
        for (int kf = 0; kf < 4; kf++)
            qf[i][kf] = *(const short8*)&Qb[(size_t)(qbase + i * 16 + lr) * 128 + kf * 32 + lg * 8];

    f32x4 o[2][8];
#pragma unroll
    for (int i = 0; i < 2; i++)
#pragma unroll
        for (int jn = 0; jn < 8; jn++) o[i][jn] = (f32x4){0.f, 0.f, 0.f, 0.f};
    float mrow[2][4], lrow[2][4];
#pragma unroll
    for (int i = 0; i < 2; i++)
#pragma unroll
        for (int r = 0; r < 4; r++) { mrow[i][r] = -__builtin_inff(); lrow[i][r] = 0.f; }

    int ntiles = qi / 2 + 1;
    for (int ti = w; ti < ntiles; ti += 4) {
        int sb = ti * 64;
        f32x4 s[2][4];
#pragma unroll
        for (int i = 0; i < 2; i++)
#pragma unroll
            for (int nf = 0; nf < 4; nf++) s[i][nf] = (f32x4){0.f, 0.f, 0.f, 0.f};
        {
            short8 kb[4][4];
#pragma unroll
            for (int nf = 0; nf < 4; nf++)
#pragma unroll
                for (int kf = 0; kf < 4; kf++)
                    kb[nf][kf] = *(const short8*)&Kb[(size_t)(sb + nf * 16 + lr) * 128 + kf * 32 + lg * 8];
#pragma unroll
            for (int kf = 0; kf < 4; kf++)
#pragma unroll
                for (int i = 0; i < 2; i++)
#pragma unroll
                    for (int nf = 0; nf < 4; nf++)
                        s[i][nf] = __builtin_amdgcn_mfma_f32_16x16x32_bf16(qf[i][kf], kb[nf][kf], s[i][nf], 0, 0, 0);
        }
        if (sb + 63 > qbase) {   // diagonal tile(s): causal mask
#pragma unroll
            for (int i = 0; i < 2; i++)
#pragma unroll
                for (int nf = 0; nf < 4; nf++)
#pragma unroll
                    for (int r = 0; r < 4; r++) {
                        int sg = sb + nf * 16 + lr;
                        int qg = qbase + i * 16 + (lg << 2) + r;
                        if (sg > qg) s[i][nf][r] = -__builtin_inff();
                    }
        }
        float alpha[2][4];
#pragma unroll
        for (int i = 0; i < 2; i++)
#pragma unroll
            for (int r = 0; r < 4; r++) {
                float pm = fmaxf(fmaxf(s[i][0][r], s[i][1][r]), fmaxf(s[i][2][r], s[i][3][r]));
                pm = fmaxf(pm, __shfl_xor(pm, 1));
                pm = fmaxf(pm, __shfl_xor(pm, 2));
                pm = fmaxf(pm, __shfl_xor(pm, 4));
                pm = fmaxf(pm, __shfl_xor(pm, 8));
                float mn = fmaxf(mrow[i][r], pm);
                alpha[i][r] = __expf(mrow[i][r] - mn);
                mrow[i][r] = mn;
            }
#pragma unroll
        for (int i = 0; i < 2; i++)
#pragma unroll
            for (int r = 0; r < 4; r++) {
                float rs = 0.f;
#pragma unroll
                for (int nf = 0; nf < 4; nf++) {
                    float p = __expf(s[i][nf][r] - mrow[i][r]);
                    s[i][nf][r] = p;
                    rs += p;
                }
                rs += __shfl_xor(rs, 1);
                rs += __shfl_xor(rs, 2);
                rs += __shfl_xor(rs, 4);
                rs += __shfl_xor(rs, 8);
                lrow[i][r] = lrow[i][r] * alpha[i][r] + rs;
            }
#pragma unroll
        for (int i = 0; i < 2; i++)
#pragma unroll
            for (int jn = 0; jn < 8; jn++)
#pragma unroll
                for (int r = 0; r < 4; r++) o[i][jn][r] *= alpha[i][r];
#pragma unroll
        for (int i = 0; i < 2; i++)
#pragma unroll
            for (int nf = 0; nf < 4; nf++)
#pragma unroll
                for (int r = 0; r < 4; r++) {
                    int row = i * 16 + (lg << 2) + r;
                    int cb2 = (nf * 16 + lr) * 2;
                    *(unsigned short*)(p_lds + swz128(row, cb2)) = f2bf(s[i][nf][r]);
                }
        asm volatile("s_waitcnt lgkmcnt(0)" ::: "memory");
        short8 pa[2][2];
#pragma unroll
        for (int i = 0; i < 2; i++)
#pragma unroll
            for (int kf = 0; kf < 2; kf++)
                pa[i][kf] = *(const short8*)(p_lds + swz128(i * 16 + lr, kf * 64 + lg * 16));
        short8 vb[8][2];
#pragma unroll
        for (int nf = 0; nf < 8; nf++)
#pragma unroll
            for (int kf = 0; kf < 2; kf++)
                vb[nf][kf] = *(const short8*)&Vt[(size_t)(nf * 16 + lr) * 2048 + sb + kf * 32 + lg * 8];
#pragma unroll
        for (int i = 0; i < 2; i++)
#pragma unroll
            for (int nf = 0; nf < 8; nf++)
#pragma unroll
                for (int kf = 0; kf < 2; kf++)
                    o[i][nf] = __builtin_amdgcn_mfma_f32_16x16x32_bf16(pa[i][kf], vb[nf][kf], o[i][nf], 0, 0, 0);
    }
#pragma unroll
    for (int i = 0; i < 2; i++)
#pragma unroll
        for (int r = 0; r < 4; r++) {
            int q = i * 16 + (lg << 2) + r;
            ml[w][0][q] = mrow[i][r];
            ml[w][1][q] = lrow[i][r];
        }
    asm volatile("s_waitcnt lgkmcnt(0)" ::: "memory");
#pragma unroll
    for (int i = 0; i < 2; i++)
#pragma unroll
        for (int jn = 0; jn < 8; jn++)
#pragma unroll
            for (int r = 0; r < 4; r++)
                o_lds[w][i * 16 + (lg << 2) + r][jn * 16 + lr] = o[i][jn][r];
    __syncthreads();
    int q = tid >> 3, h0 = (tid & 7) << 4;
    float mg = fmaxf(fmaxf(ml[0][0][q], ml[1][0][q]), fmaxf(ml[2][0][q], ml[3][0][q]));
    float scw[4], den = 0.f;
#pragma unroll
    for (int w4 = 0; w4 < 4; w4++) {
        scw[w4] = __expf(ml[w4][0][q] - mg);
        den += scw[w4] * ml[w4][1][q];
    }
    float inv = 1.0f / den;
    float* op = out + ((size_t)b * 2048 + qbase + q) * 128 + h0;
#pragma unroll
    for (int jj = 0; jj < 4; jj++) {
        f32x4 a4 = (f32x4){0.f, 0.f, 0.f, 0.f};
#pragma unroll
        for (int w4 = 0; w4 < 4; w4++) {
            f32x4 v = *(const f32x4*)&o_lds[w4][q][h0 + jj * 4];
            a4 += scw[w4] * v;
        }
        a4 *= inv;
        *(f32x4*)(op + jj * 4) = a4;
    }
}

extern "C" void kernel_launch(void* const* d_in, const int* in_sizes, int n_in,
                              void* d_out, int out_size, void* d_ws, size_t ws_size,
                              hipStream_t stream) {
    (void)in_sizes; (void)n_in; (void)out_size; (void)ws_size;
    const float* x  = (const float*)d_in[0];
    const float* Wq = (const float*)d_in[1];
    const float* bq = (const float*)d_in[2];
    const float* Wk = (const float*)d_in[3];
    const float* bk = (const float*)d_in[4];
    const float* Wv = (const float*)d_in[5];
    const float* bv = (const float*)d_in[6];
    unsigned short* ws = (unsigned short*)d_ws;
    float* out = (float*)d_out;

    wt_kernel<<<96, 256, 0, stream>>>(Wq, Wk, Wv, ws);
    qkv_kernel<<<384, 256, 0, stream>>>(x, bq, bk, bv, ws);
    attn_kernel<<<dim3(8, 64), 256, 0, stream>>>(ws, out);
}

// Round 11
// 121.425 us; speedup vs baseline: 2.0299x; 2.0299x over previous
//
#include <hip/hip_runtime.h>

typedef float f32x4 __attribute__((ext_vector_type(4)));
typedef short short8 __attribute__((ext_vector_type(8)));
typedef unsigned short ushort8 __attribute__((ext_vector_type(8)));

// ---------------- workspace layout (ushort elements) ----------------
// WTt (3 x [64 ks][128 h][32 c] bf16): 0 .. 786432
// Q  ([8*2048][128] bf16):        786432
// K  ([8*2048][128] bf16):        2883584
// Vt ([8][128][2048] bf16):       4980736
#define WS_Q  786432
#define WS_K  2883584
#define WS_VT 4980736

__device__ __forceinline__ unsigned short f2bf(float x) {
    unsigned u = __float_as_uint(x);
    u += 0x7FFFu + ((u >> 16) & 1u);      // RNE
    return (unsigned short)(u >> 16);
}

__device__ __forceinline__ short8 cvt8(float4 lo, float4 hi) {
    union { unsigned u[4]; short8 s; } r;
    asm("v_cvt_pk_bf16_f32 %0, %1, %2" : "=v"(r.u[0]) : "v"(lo.x), "v"(lo.y));
    asm("v_cvt_pk_bf16_f32 %0, %1, %2" : "=v"(r.u[1]) : "v"(lo.z), "v"(lo.w));
    asm("v_cvt_pk_bf16_f32 %0, %1, %2" : "=v"(r.u[2]) : "v"(hi.x), "v"(hi.y));
    asm("v_cvt_pk_bf16_f32 %0, %1, %2" : "=v"(r.u[3]) : "v"(hi.z), "v"(hi.w));
    return r.s;
}

// swizzle for 128-byte rows (attn P buffer)
__device__ __forceinline__ int swz128(int row, int cbyte) {
    return row * 128 + (cbyte ^ ((row & 7) << 4));
}

// ================= K0: W [2048][128] fp32 -> WTt [64 ks][128 h][32 c] bf16
__global__ __launch_bounds__(256) void wt_kernel(const float* __restrict__ Wq,
        const float* __restrict__ Wk, const float* __restrict__ Wv,
        unsigned short* __restrict__ ws) {
    __shared__ __align__(16) unsigned short tile[64][136];
    int mat = blockIdx.x >> 5, ct = blockIdx.x & 31;
    const float* W = (mat == 0) ? Wq : ((mat == 1) ? Wk : Wv);
    int cbase = ct * 64;
    int tid = threadIdx.x;
#pragma unroll
    for (int p = 0; p < 8; p++) {
        int fidx = p * 256 + tid;          // float4 index, 2048 total
        int row = fidx >> 5;               // c within tile (0..63)
        int c4 = (fidx & 31) << 2;         // h (0..124)
        float4 v = *(const float4*)&W[(size_t)(cbase + row) * 128 + c4];
        tile[row][c4 + 0] = f2bf(v.x);
        tile[row][c4 + 1] = f2bf(v.y);
        tile[row][c4 + 2] = f2bf(v.z);
        tile[row][c4 + 3] = f2bf(v.w);
    }
    __syncthreads();
    int h = tid >> 1, seg = tid & 1;
    unsigned short* dst = ws + mat * 262144 + (ct * 2 + seg) * 4096 + h * 32;
#pragma unroll
    for (int q4 = 0; q4 < 4; q4++) {
        ushort8 pk;
#pragma unroll
        for (int e = 0; e < 8; e++) pk[e] = tile[seg * 32 + q4 * 8 + e][h];
        *(ushort8*)(dst + q4 * 8) = pk;
    }
}

// ================= K1: QKV projection, 128x128 tile, depth-3 pipeline =====
// Identical to R10 EXCEPT the steady loop is unrolled by 6 = lcm(3 bufs, 2
// rA parity slots) so EVERY register-array index is compile-time constant
// (rule #20: runtime-indexed ext_vector arrays demote to scratch — R10's
// 146 MB/way spill traffic).
__global__ __launch_bounds__(256, 3) void qkv_kernel(const float* __restrict__ x,
        const float* __restrict__ bq, const float* __restrict__ bk,
        const float* __restrict__ bv, unsigned short* __restrict__ ws) {
    __shared__ __align__(16) char lds_raw[3][16384];   // 48 KB
    int bid = blockIdx.x;
    int matrix = bid >> 7;              // 0=Q 1=K 2=V
    int strip = bid & 127;              // 128-row strip of x
    const unsigned short* WTt = ws + matrix * 262144;
    const float* x0 = x + (size_t)strip * 128 * 2048;
    int tid = threadIdx.x, lane = tid & 63, wid = tid >> 6;
    int lr = lane & 15, lg = lane >> 4;
    int m0 = (wid >> 1) * 64, n0 = (wid & 1) * 64;

    // bias loads drained before the pipeline so vmcnt counts stay exact
    const float* bias = (matrix == 0) ? bq : ((matrix == 1) ? bk : bv);
    float bb[4];
#pragma unroll
    for (int j2 = 0; j2 < 4; j2++) bb[j2] = bias[n0 + j2 * 16 + lr];
    asm volatile("" : "+v"(bb[0]), "+v"(bb[1]), "+v"(bb[2]), "+v"(bb[3]));
    asm volatile("s_waitcnt vmcnt(0)" ::: "memory");

    // A staging: thread owns 16 floats (half of one 32-float row)
    int rowA = tid >> 1, hf = tid & 1;
    const float* aSrc = x0 + (size_t)rowA * 2048 + hf * 16;
    int aDst0 = rowA * 64 + (((hf * 2 + 0) ^ ((rowA >> 1) & 3)) << 4);
    int aDst1 = rowA * 64 + (((hf * 2 + 1) ^ ((rowA >> 1) & 3)) << 4);

    // B staging (DMA): 2 x 1KB chunks per wave, pre-swizzled global source
    int bsrc0, bsrc1, bdst0, bdst1;
    {
        int sig0 = wid * 64 + lane;
        int r0 = sig0 >> 2, s0 = (sig0 & 3) ^ ((r0 >> 1) & 3);
        bsrc0 = r0 * 32 + s0 * 8;  bdst0 = wid * 1024;
        int sig1 = (4 + wid) * 64 + lane;
        int r1 = sig1 >> 2, s1 = (sig1 & 3) ^ ((r1 >> 1) & 3);
        bsrc1 = r1 * 32 + s1 * 8;  bdst1 = (4 + wid) * 1024;
    }

    // fragment read offsets (bytes, swizzled). B region at +8192.
    int aOff0, aOff1, aOff2, aOff3, bOff0, bOff1, bOff2, bOff3;
    {
        int r0 = m0 + 0 * 16 + lr; aOff0 = r0 * 64 + ((lg ^ ((r0 >> 1) & 3)) << 4);
        int r1 = m0 + 1 * 16 + lr; aOff1 = r1 * 64 + ((lg ^ ((r1 >> 1) & 3)) << 4);
        int r2 = m0 + 2 * 16 + lr; aOff2 = r2 * 64 + ((lg ^ ((r2 >> 1) & 3)) << 4);
        int r3 = m0 + 3 * 16 + lr; aOff3 = r3 * 64 + ((lg ^ ((r3 >> 1) & 3)) << 4);
        int h0 = n0 + 0 * 16 + lr; bOff0 = 8192 + h0 * 64 + ((lg ^ ((h0 >> 1) & 3)) << 4);
        int h1 = n0 + 1 * 16 + lr; bOff1 = 8192 + h1 * 64 + ((lg ^ ((h1 >> 1) & 3)) << 4);
        int h2 = n0 + 2 * 16 + lr; bOff2 = 8192 + h2 * 64 + ((lg ^ ((h2 >> 1) & 3)) << 4);
        int h3 = n0 + 3 * 16 + lr; bOff3 = 8192 + h3 * 64 + ((lg ^ ((h3 >> 1) & 3)) << 4);
    }

    f32x4 acc[4][4];
#pragma unroll
    for (int i = 0; i < 4; i++)
#pragma unroll
        for (int j3 = 0; j3 < 4; j3++) acc[i][j3] = (f32x4){0.f, 0.f, 0.f, 0.f};
    float4 rA[2][4];   // ping-pong in-flight A slots; ALL indices static

#define ISSUE_A(SLOT, T) do { \
        const float* ap_ = aSrc + (size_t)(T) * 32; \
        rA[SLOT][0] = *(const float4*)ap_; \
        rA[SLOT][1] = *(const float4*)(ap_ + 4); \
        rA[SLOT][2] = *(const float4*)(ap_ + 8); \
        rA[SLOT][3] = *(const float4*)(ap_ + 12); \
    } while (0)
#define ISSUE_B(BUF, T) do { \
        const unsigned short* bs_ = WTt + (size_t)(T) * 4096; \
        char* bd_ = &lds_raw[BUF][8192]; \
        __builtin_amdgcn_global_load_lds((const __attribute__((address_space(1))) unsigned*)(bs_ + bsrc0), \
            (__attribute__((address_space(3))) unsigned*)(bd_ + bdst0), 16, 0, 0); \
        __builtin_amdgcn_global_load_lds((const __attribute__((address_space(1))) unsigned*)(bs_ + bsrc1), \
            (__attribute__((address_space(3))) unsigned*)(bd_ + bdst1), 16, 0, 0); \
    } while (0)
#define WRITE_A(SLOT, BUF) do { \
        short8 p0_ = cvt8(rA[SLOT][0], rA[SLOT][1]); \
        short8 p1_ = cvt8(rA[SLOT][2], rA[SLOT][3]); \
        *(short8*)(&lds_raw[BUF][0] + aDst0) = p0_; \
        *(short8*)(&lds_raw[BUF][0] + aDst1) = p1_; \
    } while (0)

    // body(T): frags(T) | issue grp(T+2) | 16 MFMA | wait | write A(T+1) | bar
#define QKV_BODY(U, T, STAGE, WAIT0, WRITE, BAR) do { \
        const char* Lb_ = &lds_raw[U][0]; \
        short8 av0 = *(const short8*)(Lb_ + aOff0); \
        short8 av1 = *(const short8*)(Lb_ + aOff1); \
        short8 av2 = *(const short8*)(Lb_ + aOff2); \
        short8 av3 = *(const short8*)(Lb_ + aOff3); \
        short8 bv0 = *(const short8*)(Lb_ + bOff0); \
        short8 bv1 = *(const short8*)(Lb_ + bOff1); \
        short8 bv2 = *(const short8*)(Lb_ + bOff2); \
        short8 bv3 = *(const short8*)(Lb_ + bOff3); \
        if (STAGE) { ISSUE_A((T) & 1, (T) + 2); ISSUE_B(((U) + 2) % 3, (T) + 2); } \
        acc[0][0] = __builtin_amdgcn_mfma_f32_16x16x32_bf16(av0, bv0, acc[0][0], 0, 0, 0); \
        acc[0][1] = __builtin_amdgcn_mfma_f32_16x16x32_bf16(av0, bv1, acc[0][1], 0, 0, 0); \
        acc[0][2] = __builtin_amdgcn_mfma_f32_16x16x32_bf16(av0, bv2, acc[0][2], 0, 0, 0); \
        acc[0][3] = __builtin_amdgcn_mfma_f32_16x16x32_bf16(av0, bv3, acc[0][3], 0, 0, 0); \
        acc[1][0] = __builtin_amdgcn_mfma_f32_16x16x32_bf16(av1, bv0, acc[1][0], 0, 0, 0); \
        acc[1][1] = __builtin_amdgcn_mfma_f32_16x16x32_bf16(av1, bv1, acc[1][1], 0, 0, 0); \
        acc[1][2] = __builtin_amdgcn_mfma_f32_16x16x32_bf16(av1, bv2, acc[1][2], 0, 0, 0); \
        acc[1][3] = __builtin_amdgcn_mfma_f32_16x16x32_bf16(av1, bv3, acc[1][3], 0, 0, 0); \
        acc[2][0] = __builtin_amdgcn_mfma_f32_16x16x32_bf16(av2, bv0, acc[2][0], 0, 0, 0); \
        acc[2][1] = __builtin_amdgcn_mfma_f32_16x16x32_bf16(av2, bv1, acc[2][1], 0, 0, 0); \
        acc[2][2] = __builtin_amdgcn_mfma_f32_16x16x32_bf16(av2, bv2, acc[2][2], 0, 0, 0); \
        acc[2][3] = __builtin_amdgcn_mfma_f32_16x16x32_bf16(av2, bv3, acc[2][3], 0, 0, 0); \
        acc[3][0] = __builtin_amdgcn_mfma_f32_16x16x32_bf16(av3, bv0, acc[3][0], 0, 0, 0); \
        acc[3][1] = __builtin_amdgcn_mfma_f32_16x16x32_bf16(av3, bv1, acc[3][1], 0, 0, 0); \
        acc[3][2] = __builtin_amdgcn_mfma_f32_16x16x32_bf16(av3, bv2, acc[3][2], 0, 0, 0); \
        acc[3][3] = __builtin_amdgcn_mfma_f32_16x16x32_bf16(av3, bv3, acc[3][3], 0, 0, 0); \
        if (STAGE)      { asm volatile("s_waitcnt vmcnt(6)" ::: "memory"); } \
        else if (WAIT0) { asm volatile("s_waitcnt vmcnt(0)" ::: "memory"); } \
        if (WRITE) { \
            WRITE_A(((T) + 1) & 1, ((U) + 1) % 3); \
            asm volatile("s_waitcnt lgkmcnt(0)" ::: "memory"); \
        } \
        if (BAR) __builtin_amdgcn_s_barrier(); \
    } while (0)

    // prologue: groups 0,1 in flight; tile 0's A written
    ISSUE_A(0, 0); ISSUE_B(0, 0);
    ISSUE_A(1, 1); ISSUE_B(1, 1);
    asm volatile("s_waitcnt vmcnt(6)" ::: "memory");   // group 0 landed
    WRITE_A(0, 0);
    asm volatile("s_waitcnt lgkmcnt(0)" ::: "memory");
    __builtin_amdgcn_s_barrier();

    // steady loop: 10 x 6 bodies; T0 = to6*6 is a multiple of 6, so U = k%3
    // and parity = k&1 are compile-time constants in every body instance.
    for (int to6 = 0; to6 < 10; to6++) {
        int T0 = to6 * 6;
        QKV_BODY(0, T0 + 0, true, false, true, true);
        QKV_BODY(1, T0 + 1, true, false, true, true);
        QKV_BODY(2, T0 + 2, true, false, true, true);
        QKV_BODY(0, T0 + 3, true, false, true, true);
        QKV_BODY(1, T0 + 4, true, false, true, true);
        QKV_BODY(2, T0 + 5, true, false, true, true);
    }
    QKV_BODY(0, 60, true,  false, true,  true);   // issues grp 62
    QKV_BODY(1, 61, true,  false, true,  true);   // issues grp 63; 62 landed
    QKV_BODY(2, 62, false, true,  true,  true);   // grp 63 landed
    QKV_BODY(0, 63, false, false, false, false);

    // ----- epilogue -----
    if (matrix < 2) {
        unsigned short* outp = ws + ((matrix == 0) ? WS_Q : WS_K);
        float sc = (matrix == 0) ? 0.08838834764831845f : 1.0f;   // H^-0.5 in Q
#pragma unroll
        for (int i = 0; i < 4; i++)
#pragma unroll
            for (int j3 = 0; j3 < 4; j3++) {
                int h = n0 + j3 * 16 + lr;
#pragma unroll
                for (int r = 0; r < 4; r++) {
                    size_t t = (size_t)strip * 128 + m0 + i * 16 + (lg << 2) + r;
                    outp[t * 128 + h] = f2bf((acc[i][j3][r] + bb[j3]) * sc);
                }
            }
    } else {
        __syncthreads();   // all frag reads done before LDS reuse
        unsigned short* sm = (unsigned short*)&lds_raw[0][0];   // [128][136]
#pragma unroll
        for (int i = 0; i < 4; i++)
#pragma unroll
            for (int j3 = 0; j3 < 4; j3++) {
                int h = n0 + j3 * 16 + lr;
#pragma unroll
                for (int r = 0; r < 4; r++) {
                    int tl = m0 + i * 16 + (lg << 2) + r;
                    sm[tl * 136 + h] = f2bf(acc[i][j3][r] + bb[j3]);
                }
            }
        __syncthreads();
        int h2 = tid >> 1, seg = tid & 1;
        int batch = strip >> 4;
        int tin = (strip & 15) * 128 + seg * 64;
        unsigned short* vt = ws + WS_VT + ((size_t)batch * 128 + h2) * 2048 + tin;
#pragma unroll
        for (int q8 = 0; q8 < 8; q8++) {
            ushort8 pk;
#pragma unroll
            for (int e = 0; e < 8; e++) pk[e] = sm[(seg * 64 + q8 * 8 + e) * 136 + h2];
            *(ushort8*)(vt + q8 * 8) = pk;
        }
    }
#undef QKV_BODY
#undef WRITE_A
#undef ISSUE_B
#undef ISSUE_A
}

// ================= K2: causal flash attention (unchanged) =================
__global__ __launch_bounds__(256, 2) void attn_kernel(const unsigned short* __restrict__ ws,
        float* __restrict__ out) {
    __shared__ __align__(16) float o_lds[4][32][128];   // 64 KB
    __shared__ float ml[4][2][32];
    int b = blockIdx.x;
    int qi = 63 - (int)blockIdx.y;          // longest blocks first
    int qbase = qi * 32;
    int tid = threadIdx.x, lane = tid & 63, w = tid >> 6;
    int lr = lane & 15, lg = lane >> 4;
    const unsigned short* Qb = ws + WS_Q + (size_t)b * 2048 * 128;
    const unsigned short* Kb = ws + WS_K + (size_t)b * 2048 * 128;
    const unsigned short* Vt = ws + WS_VT + (size_t)b * 128 * 2048;
    char* p_lds = (char*)&o_lds[w][0][0];   // per-wave private 4 KB

    short8 qf[2][4];
#pragma unroll
    for (int i = 0; i < 2; i++)
#pragma unroll
        for (int kf = 0; kf < 4; kf++)
            qf[i][kf] = *(const short8*)&Qb[(size_t)(qbase + i * 16 + lr) * 128 + kf * 32 + lg * 8];

    f32x4 o[2][8];
#pragma unroll
    for (int i = 0; i < 2; i++)
#pragma unroll
        for (int jn = 0; jn < 8; jn++) o[i][jn] = (f32x4){0.f, 0.f, 0.f, 0.f};
    float mrow[2][4], lrow[2][4];
#pragma unroll
    for (int i = 0; i < 2; i++)
#pragma unroll
        for (int r = 0; r < 4; r++) { mrow[i][r] = -__builtin_inff(); lrow[i][r] = 0.f; }

    int ntiles = qi / 2 + 1;
    for (int ti = w; ti < ntiles; ti += 4) {
        int sb = ti * 64;
        f32x4 s[2][4];
#pragma unroll
        for (int i = 0; i < 2; i++)
#pragma unroll
            for (int nf = 0; nf < 4; nf++) s[i][nf] = (f32x4){0.f, 0.f, 0.f, 0.f};
        {
            short8 kb[4][4];
#pragma unroll
            for (int nf = 0; nf < 4; nf++)
#pragma unroll
                for (int kf = 0; kf < 4; kf++)
                    kb[nf][kf] = *(const short8*)&Kb[(size_t)(sb + nf * 16 + lr) * 128 + kf * 32 + lg * 8];
#pragma unroll
            for (int kf = 0; kf < 4; kf++)
#pragma unroll
                for (int i = 0; i < 2; i++)
#pragma unroll
                    for (int nf = 0; nf < 4; nf++)
                        s[i][nf] = __builtin_amdgcn_mfma_f32_16x16x32_bf16(qf[i][kf], kb[nf][kf], s[i][nf], 0, 0, 0);
        }
        if (sb + 63 > qbase) {   // diagonal tile(s): causal mask
#pragma unroll
            for (int i = 0; i < 2; i++)
#pragma unroll
                for (int nf = 0; nf < 4; nf++)
#pragma unroll
                    for (int r = 0; r < 4; r++) {
                        int sg = sb + nf * 16 + lr;
                        int qg = qbase + i * 16 + (lg << 2) + r;
                        if (sg > qg) s[i][nf][r] = -__builtin_inff();
                    }
        }
        float alpha[2][4];
#pragma unroll
        for (int i = 0; i < 2; i++)
#pragma unroll
            for (int r = 0; r < 4; r++) {
                float pm = fmaxf(fmaxf(s[i][0][r], s[i][1][r]), fmaxf(s[i][2][r], s[i][3][r]));
                pm = fmaxf(pm, __shfl_xor(pm, 1));
                pm = fmaxf(pm, __shfl_xor(pm, 2));
                pm = fmaxf(pm, __shfl_xor(pm, 4));
                pm = fmaxf(pm, __shfl_xor(pm, 8));
                float mn = fmaxf(mrow[i][r], pm);
                alpha[i][r] = __expf(mrow[i][r] - mn);
                mrow[i][r] = mn;
            }
#pragma unroll
        for (int i = 0; i < 2; i++)
#pragma unroll
            for (int r = 0; r < 4; r++) {
                float rs = 0.f;
#pragma unroll
                for (int nf = 0; nf < 4; nf++) {
                    float p = __expf(s[i][nf][r] - mrow[i][r]);
                    s[i][nf][r] = p;
                    rs += p;
                }
                rs += __shfl_xor(rs, 1);
                rs += __shfl_xor(rs, 2);
                rs += __shfl_xor(rs, 4);
                rs += __shfl_xor(rs, 8);
                lrow[i][r] = lrow[i][r] * alpha[i][r] + rs;
            }
#pragma unroll
        for (int i = 0; i < 2; i++)
#pragma unroll
            for (int jn = 0; jn < 8; jn++)
#pragma unroll
                for (int r = 0; r < 4; r++) o[i][jn][r] *= alpha[i][r];
#pragma unroll
        for (int i = 0; i < 2; i++)
#pragma unroll
            for (int nf = 0; nf < 4; nf++)
#pragma unroll
                for (int r = 0; r < 4; r++) {
                    int row = i * 16 + (lg << 2) + r;
                    int cb2 = (nf * 16 + lr) * 2;
                    *(unsigned short*)(p_lds + swz128(row, cb2)) = f2bf(s[i][nf][r]);
                }
        asm volatile("s_waitcnt lgkmcnt(0)" ::: "memory");
        short8 pa[2][2];
#pragma unroll
        for (int i = 0; i < 2; i++)
#pragma unroll
            for (int kf = 0; kf < 2; kf++)
                pa[i][kf] = *(const short8*)(p_lds + swz128(i * 16 + lr, kf * 64 + lg * 16));
        short8 vb[8][2];
#pragma unroll
        for (int nf = 0; nf < 8; nf++)
#pragma unroll
            for (int kf = 0; kf < 2; kf++)
                vb[nf][kf] = *(const short8*)&Vt[(size_t)(nf * 16 + lr) * 2048 + sb + kf * 32 + lg * 8];
#pragma unroll
        for (int i = 0; i < 2; i++)
#pragma unroll
            for (int nf = 0; nf < 8; nf++)
#pragma unroll
                for (int kf = 0; kf < 2; kf++)
                    o[i][nf] = __builtin_amdgcn_mfma_f32_16x16x32_bf16(pa[i][kf], vb[nf][kf], o[i][nf], 0, 0, 0);
    }
#pragma unroll
    for (int i = 0; i < 2; i++)
#pragma unroll
        for (int r = 0; r < 4; r++) {
            int q = i * 16 + (lg << 2) + r;
            ml[w][0][q] = mrow[i][r];
            ml[w][1][q] = lrow[i][r];
        }
    asm volatile("s_waitcnt lgkmcnt(0)" ::: "memory");
#pragma unroll
    for (int i = 0; i < 2; i++)
#pragma unroll
        for (int jn = 0; jn < 8; jn++)
#pragma unroll
            for (int r = 0; r < 4; r++)
                o_lds[w][i * 16 + (lg << 2) + r][jn * 16 + lr] = o[i][jn][r];
    __syncthreads();
    int q = tid >> 3, h0 = (tid & 7) << 4;
    float mg = fmaxf(fmaxf(ml[0][0][q], ml[1][0][q]), fmaxf(ml[2][0][q], ml[3][0][q]));
    float scw[4], den = 0.f;
#pragma unroll
    for (int w4 = 0; w4 < 4; w4++) {
        scw[w4] = __expf(ml[w4][0][q] - mg);
        den += scw[w4] * ml[w4][1][q];
    }
    float inv = 1.0f / den;
    float* op = out + ((size_t)b * 2048 + qbase + q) * 128 + h0;
#pragma unroll
    for (int jj = 0; jj < 4; jj++) {
        f32x4 a4 = (f32x4){0.f, 0.f, 0.f, 0.f};
#pragma unroll
        for (int w4 = 0; w4 < 4; w4++) {
            f32x4 v = *(const f32x4*)&o_lds[w4][q][h0 + jj * 4];
            a4 += scw[w4] * v;
        }
        a4 *= inv;
        *(f32x4*)(op + jj * 4) = a4;
    }
}

extern "C" void kernel_launch(void* const* d_in, const int* in_sizes, int n_in,
                              void* d_out, int out_size, void* d_ws, size_t ws_size,
                              hipStream_t stream) {
    (void)in_sizes; (void)n_in; (void)out_size; (void)ws_size;
    const float* x  = (const float*)d_in[0];
    const float* Wq = (const float*)d_in[1];
    const float* bq = (const float*)d_in[2];
    const float* Wk = (const float*)d_in[3];
    const float* bk = (const float*)d_in[4];
    const float* Wv = (const float*)d_in[5];
    const float* bv = (const float*)d_in[6];
    unsigned short* ws = (unsigned short*)d_ws;
    float* out = (float*)d_out;

    wt_kernel<<<96, 256, 0, stream>>>(Wq, Wk, Wv, ws);
    qkv_kernel<<<384, 256, 0, stream>>>(x, bq, bk, bv, ws);
    attn_kernel<<<dim3(8, 64), 256, 0, stream>>>(ws, out);
}

// Round 12
// 113.233 us; speedup vs baseline: 2.1768x; 1.0724x over previous
//
#include <hip/hip_runtime.h>

typedef float f32x4 __attribute__((ext_vector_type(4)));
typedef short short8 __attribute__((ext_vector_type(8)));
typedef unsigned short ushort8 __attribute__((ext_vector_type(8)));

#define AS1 __attribute__((address_space(1)))
#define AS3 __attribute__((address_space(3)))

// ---------------- workspace layout (ushort elements) ----------------
// WTt (3 x [32 ks][128 h][64 c] bf16, c pre-swizzled): 0 .. 786432
// Q  ([8*2048][128] bf16):        786432
// K  ([8*2048][128] bf16):        2883584
// Vt ([8][128][2048] bf16):       4980736
#define WS_Q  786432
#define WS_K  2883584
#define WS_VT 4980736

__device__ __forceinline__ unsigned short f2bf(float x) {
    unsigned u = __float_as_uint(x);
    u += 0x7FFFu + ((u >> 16) & 1u);      // RNE
    return (unsigned short)(u >> 16);
}

__device__ __forceinline__ short8 cvt8(float4 lo, float4 hi) {
    union { unsigned u[4]; short8 s; } r;
    asm("v_cvt_pk_bf16_f32 %0, %1, %2" : "=v"(r.u[0]) : "v"(lo.x), "v"(lo.y));
    asm("v_cvt_pk_bf16_f32 %0, %1, %2" : "=v"(r.u[1]) : "v"(lo.z), "v"(lo.w));
    asm("v_cvt_pk_bf16_f32 %0, %1, %2" : "=v"(r.u[2]) : "v"(hi.x), "v"(hi.y));
    asm("v_cvt_pk_bf16_f32 %0, %1, %2" : "=v"(r.u[3]) : "v"(hi.z), "v"(hi.w));
    return r.s;
}

// swizzle for 128-byte rows (attn P buffer)
__device__ __forceinline__ int swz128(int row, int cbyte) {
    return row * 128 + (cbyte ^ ((row & 7) << 4));
}

// ====== K0: W [2048][128] fp32 -> WTt [32 ks][128 h][64 c] bf16 ===========
// c stored PRE-SWIZZLED: 8-elem group g at phys position g ^ (h & 7), so the
// qkv B-DMA is a pure linear copy and ds_reads use the same XOR (rule #21).
__global__ __launch_bounds__(256) void wt_kernel(const float* __restrict__ Wq,
        const float* __restrict__ Wk, const float* __restrict__ Wv,
        unsigned short* __restrict__ ws) {
    __shared__ __align__(16) unsigned short tile[64][136];
    int mat = blockIdx.x >> 5, ct = blockIdx.x & 31;   // ct = 64-wide k-chunk = ks
    const float* W = (mat == 0) ? Wq : ((mat == 1) ? Wk : Wv);
    int cbase = ct * 64;
    int tid = threadIdx.x;
#pragma unroll
    for (int p = 0; p < 8; p++) {
        int fidx = p * 256 + tid;          // float4 index, 2048 total
        int row = fidx >> 5;               // k within chunk (0..63)
        int c4 = (fidx & 31) << 2;         // h (0..124)
        float4 v = *(const float4*)&W[(size_t)(cbase + row) * 128 + c4];
        tile[row][c4 + 0] = f2bf(v.x);
        tile[row][c4 + 1] = f2bf(v.y);
        tile[row][c4 + 2] = f2bf(v.z);
        tile[row][c4 + 3] = f2bf(v.w);
    }
    __syncthreads();
    int h = tid >> 1, seg = tid & 1;       // h 0..127, seg: half of 64 k-cols
    unsigned short* base = ws + mat * 262144 + ct * 8192 + h * 64;
#pragma unroll
    for (int q4 = 0; q4 < 4; q4++) {
        ushort8 pk;
#pragma unroll
        for (int e = 0; e < 8; e++) pk[e] = tile[seg * 32 + q4 * 8 + e][h];
        int g = seg * 4 + q4;              // logical 8-elem group (k/8)
        *(ushort8*)(base + ((g ^ (h & 7)) << 3)) = pk;
    }
}

// ====== K1: QKV projection — 64x128 tile, BK=64, 16 MFMA/body =============
// grid 768 (3 blocks/CU, 12 waves/CU). 2 LDS buffers x 24KB (A 8KB | B 16KB).
// Per body: issue STAGE(t+1) first (4 A-float4 -> regs, 4 B-DMA linear into
// pre-swizzled storage), 12 ds_read_b128, setprio(1)+16 MFMA+setprio(0),
// vmcnt(0), cvt+2 ds_write A(t+1), lgkmcnt(0), barrier. 32 bodies.
__global__ __launch_bounds__(256, 3) void qkv_kernel(const float* __restrict__ x,
        const float* __restrict__ bq, const float* __restrict__ bk,
        const float* __restrict__ bv, unsigned short* __restrict__ ws) {
    __shared__ __align__(16) char lds[2][24576];       // 48 KB
    int bid = blockIdx.x;
    int g = bid / 24, j = bid - g * 24;
    int matrix = j >> 3;                // 0=Q 1=K 2=V; siblings 8 bids apart
    int mt = g * 8 + (j & 7);           // 64-row strip, 0..255
    const unsigned short* WTt = ws + matrix * 262144;
    const float* x0 = x + (size_t)mt * 64 * 2048;
    int tid = threadIdx.x, lane = tid & 63, wid = tid >> 6;
    int lr = lane & 15, lg = lane >> 4;
    int m0 = (wid >> 1) * 32, n0 = (wid & 1) * 64;

    // ---- A staging geometry: thread owns 16 floats of the 64x64 x-tile ---
    int rowA = tid >> 2, qa = tid & 3;
    const float* aSrc = x0 + (size_t)rowA * 2048 + qa * 16;
    int aD0 = rowA * 128 + ((((qa * 2 + 0)) ^ (rowA & 7)) << 4);
    int aD1 = rowA * 128 + ((((qa * 2 + 1)) ^ (rowA & 7)) << 4);

    // ---- fragment read offsets (bytes, 8-row XOR swizzle) ----
    int aOff00, aOff01, aOff10, aOff11;
    int bOff00, bOff01, bOff10, bOff11, bOff20, bOff21, bOff30, bOff31;
    {
        int r0 = m0 + lr, r1 = m0 + 16 + lr;
        aOff00 = r0 * 128 + (((0 * 4 + lg) ^ (r0 & 7)) << 4);
        aOff01 = r0 * 128 + (((1 * 4 + lg) ^ (r0 & 7)) << 4);
        aOff10 = r1 * 128 + (((0 * 4 + lg) ^ (r1 & 7)) << 4);
        aOff11 = r1 * 128 + (((1 * 4 + lg) ^ (r1 & 7)) << 4);
        int h0 = n0 + lr, h1 = n0 + 16 + lr, h2 = n0 + 32 + lr, h3 = n0 + 48 + lr;
        bOff00 = 8192 + h0 * 128 + (((0 * 4 + lg) ^ (h0 & 7)) << 4);
        bOff01 = 8192 + h0 * 128 + (((1 * 4 + lg) ^ (h0 & 7)) << 4);
        bOff10 = 8192 + h1 * 128 + (((0 * 4 + lg) ^ (h1 & 7)) << 4);
        bOff11 = 8192 + h1 * 128 + (((1 * 4 + lg) ^ (h1 & 7)) << 4);
        bOff20 = 8192 + h2 * 128 + (((0 * 4 + lg) ^ (h2 & 7)) << 4);
        bOff21 = 8192 + h2 * 128 + (((1 * 4 + lg) ^ (h2 & 7)) << 4);
        bOff30 = 8192 + h3 * 128 + (((0 * 4 + lg) ^ (h3 & 7)) << 4);
        bOff31 = 8192 + h3 * 128 + (((1 * 4 + lg) ^ (h3 & 7)) << 4);
    }

    f32x4 acc[2][4];
#pragma unroll
    for (int i = 0; i < 2; i++)
#pragma unroll
        for (int j3 = 0; j3 < 4; j3++) acc[i][j3] = (f32x4){0.f, 0.f, 0.f, 0.f};
    float4 rA0, rA1, rA2, rA3;     // single in-flight A slot (issued & written
                                   // within the same body -> no ping-pong)

#define ISSUE_AB(BUF, T) do { \
        const float* ap_ = aSrc + (size_t)(T) * 64; \
        rA0 = *(const float4*)ap_;        rA1 = *(const float4*)(ap_ + 4); \
        rA2 = *(const float4*)(ap_ + 8);  rA3 = *(const float4*)(ap_ + 12); \
        const unsigned short* bs_ = WTt + (size_t)(T) * 8192 + tid * 8; \
        char* bd_ = &lds[BUF][8192] + tid * 16; \
        __builtin_amdgcn_global_load_lds((const AS1 unsigned*)(bs_), \
            (AS3 unsigned*)(bd_), 16, 0, 0); \
        __builtin_amdgcn_global_load_lds((const AS1 unsigned*)(bs_ + 2048), \
            (AS3 unsigned*)(bd_ + 4096), 16, 0, 0); \
        __builtin_amdgcn_global_load_lds((const AS1 unsigned*)(bs_ + 4096), \
            (AS3 unsigned*)(bd_ + 8192), 16, 0, 0); \
        __builtin_amdgcn_global_load_lds((const AS1 unsigned*)(bs_ + 6144), \
            (AS3 unsigned*)(bd_ + 12288), 16, 0, 0); \
    } while (0)
#define WRITE_A(BUF) do { \
        short8 p0_ = cvt8(rA0, rA1); \
        short8 p1_ = cvt8(rA2, rA3); \
        *(short8*)(&lds[BUF][0] + aD0) = p0_; \
        *(short8*)(&lds[BUF][0] + aD1) = p1_; \
    } while (0)

#define QKV_BODY(T, CUR, STAGE, BAR) do { \
        if (STAGE) ISSUE_AB((CUR) ^ 1, (T) + 1); \
        const char* Lb_ = &lds[CUR][0]; \
        short8 a00 = *(const short8*)(Lb_ + aOff00); \
        short8 a01 = *(const short8*)(Lb_ + aOff01); \
        short8 a10 = *(const short8*)(Lb_ + aOff10); \
        short8 a11 = *(const short8*)(Lb_ + aOff11); \
        short8 b00 = *(const short8*)(Lb_ + bOff00); \
        short8 b01 = *(const short8*)(Lb_ + bOff01); \
        short8 b10 = *(const short8*)(Lb_ + bOff10); \
        short8 b11 = *(const short8*)(Lb_ + bOff11); \
        short8 b20 = *(const short8*)(Lb_ + bOff20); \
        short8 b21 = *(const short8*)(Lb_ + bOff21); \
        short8 b30 = *(const short8*)(Lb_ + bOff30); \
        short8 b31 = *(const short8*)(Lb_ + bOff31); \
        __builtin_amdgcn_s_setprio(1); \
        acc[0][0] = __builtin_amdgcn_mfma_f32_16x16x32_bf16(a00, b00, acc[0][0], 0, 0, 0); \
        acc[0][1] = __builtin_amdgcn_mfma_f32_16x16x32_bf16(a00, b10, acc[0][1], 0, 0, 0); \
        acc[0][2] = __builtin_amdgcn_mfma_f32_16x16x32_bf16(a00, b20, acc[0][2], 0, 0, 0); \
        acc[0][3] = __builtin_amdgcn_mfma_f32_16x16x32_bf16(a00, b30, acc[0][3], 0, 0, 0); \
        acc[1][0] = __builtin_amdgcn_mfma_f32_16x16x32_bf16(a10, b00, acc[1][0], 0, 0, 0); \
        acc[1][1] = __builtin_amdgcn_mfma_f32_16x16x32_bf16(a10, b10, acc[1][1], 0, 0, 0); \
        acc[1][2] = __builtin_amdgcn_mfma_f32_16x16x32_bf16(a10, b20, acc[1][2], 0, 0, 0); \
        acc[1][3] = __builtin_amdgcn_mfma_f32_16x16x32_bf16(a10, b30, acc[1][3], 0, 0, 0); \
        acc[0][0] = __builtin_amdgcn_mfma_f32_16x16x32_bf16(a01, b01, acc[0][0], 0, 0, 0); \
        acc[0][1] = __builtin_amdgcn_mfma_f32_16x16x32_bf16(a01, b11, acc[0][1], 0, 0, 0); \
        acc[0][2] = __builtin_amdgcn_mfma_f32_16x16x32_bf16(a01, b21, acc[0][2], 0, 0, 0); \
        acc[0][3] = __builtin_amdgcn_mfma_f32_16x16x32_bf16(a01, b31, acc[0][3], 0, 0, 0); \
        acc[1][0] = __builtin_amdgcn_mfma_f32_16x16x32_bf16(a11, b01, acc[1][0], 0, 0, 0); \
        acc[1][1] = __builtin_amdgcn_mfma_f32_16x16x32_bf16(a11, b11, acc[1][1], 0, 0, 0); \
        acc[1][2] = __builtin_amdgcn_mfma_f32_16x16x32_bf16(a11, b21, acc[1][2], 0, 0, 0); \
        acc[1][3] = __builtin_amdgcn_mfma_f32_16x16x32_bf16(a11, b31, acc[1][3], 0, 0, 0); \
        __builtin_amdgcn_s_setprio(0); \
        if (STAGE) { \
            asm volatile("s_waitcnt vmcnt(0)" ::: "memory"); \
            WRITE_A((CUR) ^ 1); \
            asm volatile("s_waitcnt lgkmcnt(0)" ::: "memory"); \
        } \
        if (BAR) __builtin_amdgcn_s_barrier(); \
    } while (0)

    // prologue: stage tile 0 into buffer 0
    ISSUE_AB(0, 0);
    asm volatile("s_waitcnt vmcnt(0)" ::: "memory");
    WRITE_A(0);
    asm volatile("s_waitcnt lgkmcnt(0)" ::: "memory");
    __builtin_amdgcn_s_barrier();

    for (int t2 = 0; t2 < 15; t2++) {
        int t = t2 * 2;
        QKV_BODY(t + 0, 0, true, true);
        QKV_BODY(t + 1, 1, true, true);
    }
    QKV_BODY(30, 0, true,  true);    // stages t=31 into buffer 1
    QKV_BODY(31, 1, false, false);

    // ----- epilogue -----
    const float* bias = (matrix == 0) ? bq : ((matrix == 1) ? bk : bv);
    float bb[4];
#pragma unroll
    for (int j3 = 0; j3 < 4; j3++) bb[j3] = bias[n0 + j3 * 16 + lr];
    if (matrix < 2) {
        unsigned short* outp = ws + ((matrix == 0) ? WS_Q : WS_K);
        float sc = (matrix == 0) ? 0.08838834764831845f : 1.0f;  // H^-0.5 in Q
#pragma unroll
        for (int i = 0; i < 2; i++)
#pragma unroll
            for (int j3 = 0; j3 < 4; j3++) {
                int h = n0 + j3 * 16 + lr;
#pragma unroll
                for (int r = 0; r < 4; r++) {
                    size_t t = (size_t)mt * 64 + m0 + i * 16 + (lg << 2) + r;
                    outp[t * 128 + h] = f2bf((acc[i][j3][r] + bb[j3]) * sc);
                }
            }
    } else {
        __syncthreads();
        unsigned short* sm = (unsigned short*)&lds[0][0];   // [64][136]
#pragma unroll
        for (int i = 0; i < 2; i++)
#pragma unroll
            for (int j3 = 0; j3 < 4; j3++) {
                int h = n0 + j3 * 16 + lr;
#pragma unroll
                for (int r = 0; r < 4; r++) {
                    int tl = m0 + i * 16 + (lg << 2) + r;
                    sm[tl * 136 + h] = f2bf(acc[i][j3][r] + bb[j3]);
                }
            }
        __syncthreads();
        int h = tid & 127, seg = tid >> 7;
        int b2 = mt >> 5;
        int tin = (mt & 31) * 64 + seg * 32;
        unsigned short* vt = ws + WS_VT + ((size_t)b2 * 128 + h) * 2048 + tin;
#pragma unroll
        for (int q4 = 0; q4 < 4; q4++) {
            ushort8 pk;
#pragma unroll
            for (int e = 0; e < 8; e++) pk[e] = sm[(seg * 32 + q4 * 8 + e) * 136 + h];
            *(ushort8*)(vt + q4 * 8) = pk;
        }
    }
#undef QKV_BODY
#undef WRITE_A
#undef ISSUE_AB
}

// ================= K2: causal flash attention (unchanged) =================
__global__ __launch_bounds__(256, 2) void attn_kernel(const unsigned short* __restrict__ ws,
        float* __restrict__ out) {
    __shared__ __align__(16) float o_lds[4][32][128];   // 64 KB
    __shared__ float ml[4][2][32];
    int b = blockIdx.x;
    int qi = 63 - (int)blockIdx.y;          // longest blocks first
    int qbase = qi * 32;
    int tid = threadIdx.x, lane = tid & 63, w = tid >> 6;
    int lr = lane & 15, lg = lane >> 4;
    const unsigned short* Qb = ws + WS_Q + (size_t)b * 2048 * 128;
    const unsigned short* Kb = ws + WS_K + (size_t)b * 2048 * 128;
    const unsigned short* Vt = ws + WS_VT + (size_t)b * 128 * 2048;
    char* p_lds = (char*)&o_lds[w][0][0];   // per-wave private 4 KB

    short8 qf[2][4];
#pragma unroll
    for (int i = 0; i < 2; i++)
#pragma unroll
        for (int kf = 0; kf < 4; kf++)
            qf[i][kf] = *(const short8*)&Qb[(size_t)(qbase + i * 16 + lr) * 128 + kf * 32 + lg * 8];

    f32x4 o[2][8];
#pragma unroll
    for (int i = 0; i < 2; i++)
#pragma unroll
        for (int jn = 0; jn < 8; jn++) o[i][jn] = (f32x4){0.f, 0.f, 0.f, 0.f};
    float mrow[2][4], lrow[2][4];
#pragma unroll
    for (int i = 0; i < 2; i++)
#pragma unroll
        for (int r = 0; r < 4; r++) { mrow[i][r] = -__builtin_inff(); lrow[i][r] = 0.f; }

    int ntiles = qi / 2 + 1;
    for (int ti = w; ti < ntiles; ti += 4) {
        int sb = ti * 64;
        f32x4 s[2][4];
#pragma unroll
        for (int i = 0; i < 2; i++)
#pragma unroll
            for (int nf = 0; nf < 4; nf++) s[i][nf] = (f32x4){0.f, 0.f, 0.f, 0.f};
        {
            short8 kb[4][4];
#pragma unroll
            for (int nf = 0; nf < 4; nf++)
#pragma unroll
                for (int kf = 0; kf < 4; kf++)
                    kb[nf][kf] = *(const short8*)&Kb[(size_t)(sb + nf * 16 + lr) * 128 + kf * 32 + lg * 8];
#pragma unroll
            for (int kf = 0; kf < 4; kf++)
#pragma unroll
                for (int i = 0; i < 2; i++)
#pragma unroll
                    for (int nf = 0; nf < 4; nf++)
                        s[i][nf] = __builtin_amdgcn_mfma_f32_16x16x32_bf16(qf[i][kf], kb[nf][kf], s[i][nf], 0, 0, 0);
        }
        if (sb + 63 > qbase) {   // diagonal tile(s): causal mask
#pragma unroll
            for (int i = 0; i < 2; i++)
#pragma unroll
                for (int nf = 0; nf < 4; nf++)
#pragma unroll
                    for (int r = 0; r < 4; r++) {
                        int sg = sb + nf * 16 + lr;
                        int qg = qbase + i * 16 + (lg << 2) + r;
                        if (sg > qg) s[i][nf][r] = -__builtin_inff();
                    }
        }
        float alpha[2][4];
#pragma unroll
        for (int i = 0; i < 2; i++)
#pragma unroll
            for (int r = 0; r < 4; r++) {
                float pm = fmaxf(fmaxf(s[i][0][r], s[i][1][r]), fmaxf(s[i][2][r], s[i][3][r]));
                pm = fmaxf(pm, __shfl_xor(pm, 1));
                pm = fmaxf(pm, __shfl_xor(pm, 2));
                pm = fmaxf(pm, __shfl_xor(pm, 4));
                pm = fmaxf(pm, __shfl_xor(pm, 8));
                float mn = fmaxf(mrow[i][r], pm);
                alpha[i][r] = __expf(mrow[i][r] - mn);
                mrow[i][r] = mn;
            }
#pragma unroll
        for (int i = 0; i < 2; i++)
#pragma unroll
            for (int r = 0; r < 4; r++) {
                float rs = 0.f;
#pragma unroll
                for (int nf = 0; nf < 4; nf++) {
                    float p = __expf(s[i][nf][r] - mrow[i][r]);
                    s[i][nf][r] = p;
                    rs += p;
                }
                rs += __shfl_xor(rs, 1);
                rs += __shfl_xor(rs, 2);
                rs += __shfl_xor(rs, 4);
                rs += __shfl_xor(rs, 8);
                lrow[i][r] = lrow[i][r] * alpha[i][r] + rs;
            }
#pragma unroll
        for (int i = 0; i < 2; i++)
#pragma unroll
            for (int jn = 0; jn < 8; jn++)
#pragma unroll
                for (int r = 0; r < 4; r++) o[i][jn][r] *= alpha[i][r];
#pragma unroll
        for (int i = 0; i < 2; i++)
#pragma unroll
            for (int nf = 0; nf < 4; nf++)
#pragma unroll
                for (int r = 0; r < 4; r++) {
                    int row = i * 16 + (lg << 2) + r;
                    int cb2 = (nf * 16 + lr) * 2;
                    *(unsigned short*)(p_lds + swz128(row, cb2)) = f2bf(s[i][nf][r]);
                }
        asm volatile("s_waitcnt lgkmcnt(0)" ::: "memory");
        short8 pa[2][2];
#pragma unroll
        for (int i = 0; i < 2; i++)
#pragma unroll
            for (int kf = 0; kf < 2; kf++)
                pa[i][kf] = *(const short8*)(p_lds + swz128(i * 16 + lr, kf * 64 + lg * 16));
        short8 vb[8][2];
#pragma unroll
        for (int nf = 0; nf < 8; nf++)
#pragma unroll
            for (int kf = 0; kf < 2; kf++)
                vb[nf][kf] = *(const short8*)&Vt[(size_t)(nf * 16 + lr) * 2048 + sb + kf * 32 + lg * 8];
#pragma unroll
        for (int i = 0; i < 2; i++)
#pragma unroll
            for (int nf = 0; nf < 8; nf++)
#pragma unroll
                for (int kf = 0; kf < 2; kf++)
                    o[i][nf] = __builtin_amdgcn_mfma_f32_16x16x32_bf16(pa[i][kf], vb[nf][kf], o[i][nf], 0, 0, 0);
    }
#pragma unroll
    for (int i = 0; i < 2; i++)
#pragma unroll
        for (int r = 0; r < 4; r++) {
            int q = i * 16 + (lg << 2) + r;
            ml[w][0][q] = mrow[i][r];
            ml[w][1][q] = lrow[i][r];
        }
    asm volatile("s_waitcnt lgkmcnt(0)" ::: "memory");
#pragma unroll
    for (int i = 0; i < 2; i++)
#pragma unroll
        for (int jn = 0; jn < 8; jn++)
#pragma unroll
            for (int r = 0; r < 4; r++)
                o_lds[w][i * 16 + (lg << 2) + r][jn * 16 + lr] = o[i][jn][r];
    __syncthreads();
    int q = tid >> 3, h0 = (tid & 7) << 4;
    float mg = fmaxf(fmaxf(ml[0][0][q], ml[1][0][q]), fmaxf(ml[2][0][q], ml[3][0][q]));
    float scw[4], den = 0.f;
#pragma unroll
    for (int w4 = 0; w4 < 4; w4++) {
        scw[w4] = __expf(ml[w4][0][q] - mg);
        den += scw[w4] * ml[w4][1][q];
    }
    float inv = 1.0f / den;
    float* op = out + ((size_t)b * 2048 + qbase + q) * 128 + h0;
#pragma unroll
    for (int jj = 0; jj < 4; jj++) {
        f32x4 a4 = (f32x4){0.f, 0.f, 0.f, 0.f};
#pragma unroll
        for (int w4 = 0; w4 < 4; w4++) {
            f32x4 v = *(const f32x4*)&o_lds[w4][q][h0 + jj * 4];
            a4 += scw[w4] * v;
        }
        a4 *= inv;
        *(f32x4*)(op + jj * 4) = a4;
    }
}

extern "C" void kernel_launch(void* const* d_in, const int* in_sizes, int n_in,
                              void* d_out, int out_size, void* d_ws, size_t ws_size,
                              hipStream_t stream) {
    (void)in_sizes; (void)n_in; (void)out_size; (void)ws_size;
    const float* x  = (const float*)d_in[0];
    const float* Wq = (const float*)d_in[1];
    const float* bq = (const float*)d_in[2];
    const float* Wk = (const float*)d_in[3];
    const float* bk = (const float*)d_in[4];
    const float* Wv = (const float*)d_in[5];
    const float* bv = (const float*)d_in[6];
    unsigned short* ws = (unsigned short*)d_ws;
    float* out = (float*)d_out;

    wt_kernel<<<96, 256, 0, stream>>>(Wq, Wk, Wv, ws);
    qkv_kernel<<<768, 256, 0, stream>>>(x, bq, bk, bv, ws);
    attn_kernel<<<dim3(8, 64), 256, 0, stream>>>(ws, out);
}

// Round 13
// 110.776 us; speedup vs baseline: 2.2250x; 1.0222x over previous
//
#include <hip/hip_runtime.h>

typedef float f32x4 __attribute__((ext_vector_type(4)));
typedef short short8 __attribute__((ext_vector_type(8)));
typedef unsigned short ushort8 __attribute__((ext_vector_type(8)));

#define AS1 __attribute__((address_space(1)))
#define AS3 __attribute__((address_space(3)))

// ---------------- workspace layout (ushort elements) ----------------
// WTt (3 x [64 ks][128 h][32 c] bf16, unit-XOR at rest): 0 .. 786432
// Q  ([8*2048][128] bf16):        786432
// K  ([8*2048][128] bf16):        2883584
// Vt ([8][128][2048] bf16):       4980736
#define WS_Q  786432
#define WS_K  2883584
#define WS_VT 4980736

__device__ __forceinline__ unsigned short f2bf(float x) {
    unsigned u = __float_as_uint(x);
    u += 0x7FFFu + ((u >> 16) & 1u);      // RNE
    return (unsigned short)(u >> 16);
}

__device__ __forceinline__ short8 cvt8(float4 lo, float4 hi) {
    union { unsigned u[4]; short8 s; } r;
    asm("v_cvt_pk_bf16_f32 %0, %1, %2" : "=v"(r.u[0]) : "v"(lo.x), "v"(lo.y));
    asm("v_cvt_pk_bf16_f32 %0, %1, %2" : "=v"(r.u[1]) : "v"(lo.z), "v"(lo.w));
    asm("v_cvt_pk_bf16_f32 %0, %1, %2" : "=v"(r.u[2]) : "v"(hi.x), "v"(hi.y));
    asm("v_cvt_pk_bf16_f32 %0, %1, %2" : "=v"(r.u[3]) : "v"(hi.z), "v"(hi.w));
    return r.s;
}

// swizzle for 128-byte rows (attn P buffer)
__device__ __forceinline__ int swz128(int row, int cbyte) {
    return row * 128 + (cbyte ^ ((row & 7) << 4));
}

// ====== K0: W [2048][128] fp32 -> WTt [64 ks][128 h][32 c] bf16 ===========
// 16B-unit u (8 bf16) of row h stored at phys unit u ^ ((h>>1)&3): the qkv
// B-DMA is a pure linear copy; ds_reads apply the same XOR (rule #21).
__global__ __launch_bounds__(256) void wt_kernel(const float* __restrict__ Wq,
        const float* __restrict__ Wk, const float* __restrict__ Wv,
        unsigned short* __restrict__ ws) {
    __shared__ __align__(16) unsigned short tile[64][136];
    int mat = blockIdx.x >> 5, ct = blockIdx.x & 31;   // ct = 64-wide k-chunk
    const float* W = (mat == 0) ? Wq : ((mat == 1) ? Wk : Wv);
    int cbase = ct * 64;
    int tid = threadIdx.x;
#pragma unroll
    for (int p = 0; p < 8; p++) {
        int fidx = p * 256 + tid;          // float4 index, 2048 total
        int row = fidx >> 5;               // k within chunk (0..63)
        int c4 = (fidx & 31) << 2;         // h (0..124)
        float4 v = *(const float4*)&W[(size_t)(cbase + row) * 128 + c4];
        tile[row][c4 + 0] = f2bf(v.x);
        tile[row][c4 + 1] = f2bf(v.y);
        tile[row][c4 + 2] = f2bf(v.z);
        tile[row][c4 + 3] = f2bf(v.w);
    }
    __syncthreads();
    int h = tid >> 1, seg = tid & 1;       // seg: which 32-wide ks half
    int ks = ct * 2 + seg;
    unsigned short* base = ws + mat * 262144 + ks * 4096 + h * 32;
    int hx = (h >> 1) & 3;
#pragma unroll
    for (int u = 0; u < 4; u++) {
        ushort8 pk;
#pragma unroll
        for (int e = 0; e < 8; e++) pk[e] = tile[seg * 32 + u * 8 + e][h];
        *(ushort8*)(base + ((u ^ hx) << 3)) = pk;
    }
}

// ====== K1: QKV projection — pure-DMA staging, counted vmcnt ==============
// 64x128 tile, BK=32, 64 bodies, grid 768 (3 blocks/CU). 3 LDS buffers x
// 16KB (A fp32 8KB | B bf16 8KB). Staging = 4 global_load_lds per thread
// per body (2 A + 2 B), ZERO ds_write / VGPR roundtrip / lgkm. Body t:
// issue stage(t+2) -> buf (t+2)%3, 8 ds_read_b128 (XOR-swizzled), cvt at
// consume, 8 MFMA, vmcnt(4) [= stage(t+1) landed], raw s_barrier + fence.
// A's bank swizzle is applied on the DMA SOURCE (involution, rule #21):
// unit (r,pPhys) fetches logical col-unit c = pPhys ^ (r&7); 8-lane groups
// still read one 128B line -> coalescing preserved.
__global__ __launch_bounds__(256, 3) void qkv_kernel(const float* __restrict__ x,
        const float* __restrict__ bq, const float* __restrict__ bk,
        const float* __restrict__ bv, unsigned short* __restrict__ ws) {
    __shared__ __align__(16) char lds[3][16384];       // 48 KB
    int bid = blockIdx.x;
    int g = bid / 24, j = bid - g * 24;
    int matrix = j >> 3;                // 0=Q 1=K 2=V; siblings 8 bids apart
    int mt = g * 8 + (j & 7);           // 64-row strip, 0..255
    const unsigned short* WTt = ws + matrix * 262144;
    const float* x0 = x + (size_t)mt * 64 * 2048;
    int tid = threadIdx.x, lane = tid & 63, wid = tid >> 6;
    int lr = lane & 15, lg = lane >> 4;
    int m0 = (wid >> 1) * 32, n0 = (wid & 1) * 64;

    // ---- A DMA geometry: unit d = tid (rows 0..31) and tid+256 (rows 32..63)
    int rA = tid >> 3;                     // row 0..31 (second DMA: +32)
    int pA = tid & 7;                      // physical 16B unit in row
    int cA = pA ^ (rA & 7);                // logical col-unit (XOR involution)
    const float* aSrc0 = x0 + (size_t)rA * 2048 + cA * 4;
    const float* aSrc1 = aSrc0 + (size_t)32 * 2048;   // (rA+32)&7 == rA&7
    int aDst0 = tid * 16, aDst1 = tid * 16 + 4096;

    // ---- B DMA geometry: pure linear copy of the 8KB pre-swizzled block
    int bDst0 = 8192 + tid * 16, bDst1 = 8192 + 4096 + tid * 16;

    // ---- fragment read offsets (bytes, XOR-swizzled) ----
    int aOff00, aOff01, aOff10, aOff11, bOff0, bOff1, bOff2, bOff3;
    {
        int r0 = m0 + lr, r1 = m0 + 16 + lr;
        aOff00 = r0 * 128 + (((lg * 2 + 0) ^ (r0 & 7)) << 4);
        aOff01 = r0 * 128 + (((lg * 2 + 1) ^ (r0 & 7)) << 4);
        aOff10 = r1 * 128 + (((lg * 2 + 0) ^ (r1 & 7)) << 4);
        aOff11 = r1 * 128 + (((lg * 2 + 1) ^ (r1 & 7)) << 4);
        int h0 = n0 + lr, h1 = n0 + 16 + lr, h2 = n0 + 32 + lr, h3 = n0 + 48 + lr;
        bOff0 = 8192 + h0 * 64 + ((lg ^ ((h0 >> 1) & 3)) << 4);
        bOff1 = 8192 + h1 * 64 + ((lg ^ ((h1 >> 1) & 3)) << 4);
        bOff2 = 8192 + h2 * 64 + ((lg ^ ((h2 >> 1) & 3)) << 4);
        bOff3 = 8192 + h3 * 64 + ((lg ^ ((h3 >> 1) & 3)) << 4);
    }

    f32x4 acc[2][4];
#pragma unroll
    for (int i = 0; i < 2; i++)
#pragma unroll
        for (int j3 = 0; j3 < 4; j3++) acc[i][j3] = (f32x4){0.f, 0.f, 0.f, 0.f};

#define ISSUE(BUF, T) do { \
        char* Lb_ = &lds[BUF][0]; \
        const float* a0_ = aSrc0 + (size_t)(T) * 32; \
        const float* a1_ = aSrc1 + (size_t)(T) * 32; \
        __builtin_amdgcn_global_load_lds((const AS1 unsigned*)a0_, \
            (AS3 unsigned*)(Lb_ + aDst0), 16, 0, 0); \
        __builtin_amdgcn_global_load_lds((const AS1 unsigned*)a1_, \
            (AS3 unsigned*)(Lb_ + aDst1), 16, 0, 0); \
        const unsigned short* bs_ = WTt + (size_t)(T) * 4096 + tid * 8; \
        __builtin_amdgcn_global_load_lds((const AS1 unsigned*)bs_, \
            (AS3 unsigned*)(Lb_ + bDst0), 16, 0, 0); \
        __builtin_amdgcn_global_load_lds((const AS1 unsigned*)(bs_ + 2048), \
            (AS3 unsigned*)(Lb_ + bDst1), 16, 0, 0); \
    } while (0)

    // WAITN: 4 = steady (t+1 landed, t+2 in flight), 0 = tail drain, -1 = none
#define BODY(U, T, STAGE, WAITN, BAR) do { \
        if (STAGE) ISSUE(((U) + 2) % 3, (T) + 2); \
        const char* Lb_ = &lds[U][0]; \
        float4 alo0 = *(const float4*)(Lb_ + aOff00); \
        float4 ahi0 = *(const float4*)(Lb_ + aOff01); \
        float4 alo1 = *(const float4*)(Lb_ + aOff10); \
        float4 ahi1 = *(const float4*)(Lb_ + aOff11); \
        short8 b0 = *(const short8*)(Lb_ + bOff0); \
        short8 b1 = *(const short8*)(Lb_ + bOff1); \
        short8 b2 = *(const short8*)(Lb_ + bOff2); \
        short8 b3 = *(const short8*)(Lb_ + bOff3); \
        short8 a0 = cvt8(alo0, ahi0); \
        short8 a1 = cvt8(alo1, ahi1); \
        __builtin_amdgcn_s_setprio(1); \
        acc[0][0] = __builtin_amdgcn_mfma_f32_16x16x32_bf16(a0, b0, acc[0][0], 0, 0, 0); \
        acc[0][1] = __builtin_amdgcn_mfma_f32_16x16x32_bf16(a0, b1, acc[0][1], 0, 0, 0); \
        acc[0][2] = __builtin_amdgcn_mfma_f32_16x16x32_bf16(a0, b2, acc[0][2], 0, 0, 0); \
        acc[0][3] = __builtin_amdgcn_mfma_f32_16x16x32_bf16(a0, b3, acc[0][3], 0, 0, 0); \
        acc[1][0] = __builtin_amdgcn_mfma_f32_16x16x32_bf16(a1, b0, acc[1][0], 0, 0, 0); \
        acc[1][1] = __builtin_amdgcn_mfma_f32_16x16x32_bf16(a1, b1, acc[1][1], 0, 0, 0); \
        acc[1][2] = __builtin_amdgcn_mfma_f32_16x16x32_bf16(a1, b2, acc[1][2], 0, 0, 0); \
        acc[1][3] = __builtin_amdgcn_mfma_f32_16x16x32_bf16(a1, b3, acc[1][3], 0, 0, 0); \
        __builtin_amdgcn_s_setprio(0); \
        if ((WAITN) == 4)      { asm volatile("s_waitcnt vmcnt(4)" ::: "memory"); } \
        else if ((WAITN) == 0) { asm volatile("s_waitcnt vmcnt(0)" ::: "memory"); } \
        if (BAR) { \
            __builtin_amdgcn_s_barrier(); \
            asm volatile("" ::: "memory");   /* no hoisting across barrier */ \
        } \
    } while (0)

    // prologue: tiles 0,1 in flight; wait tile 0
    ISSUE(0, 0);
    ISSUE(1, 1);
    asm volatile("s_waitcnt vmcnt(4)" ::: "memory");
    __builtin_amdgcn_s_barrier();
    asm volatile("" ::: "memory");

    for (int t3 = 0; t3 < 20; t3++) {
        int T0 = t3 * 3;
        BODY(0, T0 + 0, true, 4, true);
        BODY(1, T0 + 1, true, 4, true);
        BODY(2, T0 + 2, true, 4, true);
    }
    BODY(0, 60, true,  4,  true);   // stages 62
    BODY(1, 61, true,  4,  true);   // stages 63; 62 landed
    BODY(2, 62, false, 0,  true);   // 63 landed
    BODY(0, 63, false, -1, false);
#undef BODY
#undef ISSUE

    // ----- epilogue -----
    const float* bias = (matrix == 0) ? bq : ((matrix == 1) ? bk : bv);
    float bb[4];
#pragma unroll
    for (int j3 = 0; j3 < 4; j3++) bb[j3] = bias[n0 + j3 * 16 + lr];
    if (matrix < 2) {
        unsigned short* outp = ws + ((matrix == 0) ? WS_Q : WS_K);
        float sc = (matrix == 0) ? 0.08838834764831845f : 1.0f;  // H^-0.5 in Q
#pragma unroll
        for (int i = 0; i < 2; i++)
#pragma unroll
            for (int j3 = 0; j3 < 4; j3++) {
                int h = n0 + j3 * 16 + lr;
#pragma unroll
                for (int r = 0; r < 4; r++) {
                    size_t t = (size_t)mt * 64 + m0 + i * 16 + (lg << 2) + r;
                    outp[t * 128 + h] = f2bf((acc[i][j3][r] + bb[j3]) * sc);
                }
            }
    } else {
        __syncthreads();
        unsigned short* sm = (unsigned short*)&lds[0][0];   // [64][136]
#pragma unroll
        for (int i = 0; i < 2; i++)
#pragma unroll
            for (int j3 = 0; j3 < 4; j3++) {
                int h = n0 + j3 * 16 + lr;
#pragma unroll
                for (int r = 0; r < 4; r++) {
                    int tl = m0 + i * 16 + (lg << 2) + r;
                    sm[tl * 136 + h] = f2bf(acc[i][j3][r] + bb[j3]);
                }
            }
        __syncthreads();
        int h = tid & 127, seg = tid >> 7;
        int b2 = mt >> 5;
        int tin = (mt & 31) * 64 + seg * 32;
        unsigned short* vt = ws + WS_VT + ((size_t)b2 * 128 + h) * 2048 + tin;
#pragma unroll
        for (int q4 = 0; q4 < 4; q4++) {
            ushort8 pk;
#pragma unroll
            for (int e = 0; e < 8; e++) pk[e] = sm[(seg * 32 + q4 * 8 + e) * 136 + h];
            *(ushort8*)(vt + q4 * 8) = pk;
        }
    }
}

// ================= K2: causal flash attention (unchanged) =================
__global__ __launch_bounds__(256, 2) void attn_kernel(const unsigned short* __restrict__ ws,
        float* __restrict__ out) {
    __shared__ __align__(16) float o_lds[4][32][128];   // 64 KB
    __shared__ float ml[4][2][32];
    int b = blockIdx.x;
    int qi = 63 - (int)blockIdx.y;          // longest blocks first
    int qbase = qi * 32;
    int tid = threadIdx.x, lane = tid & 63, w = tid >> 6;
    int lr = lane & 15, lg = lane >> 4;
    const unsigned short* Qb = ws + WS_Q + (size_t)b * 2048 * 128;
    const unsigned short* Kb = ws + WS_K + (size_t)b * 2048 * 128;
    const unsigned short* Vt = ws + WS_VT + (size_t)b * 128 * 2048;
    char* p_lds = (char*)&o_lds[w][0][0];   // per-wave private 4 KB

    short8 qf[2][4];
#pragma unroll
    for (int i = 0; i < 2; i++)
#pragma unroll
        for (int kf = 0; kf < 4; kf++)
            qf[i][kf] = *(const short8*)&Qb[(size_t)(qbase + i * 16 + lr) * 128 + kf * 32 + lg * 8];

    f32x4 o[2][8];
#pragma unroll
    for (int i = 0; i < 2; i++)
#pragma unroll
        for (int jn = 0; jn < 8; jn++) o[i][jn] = (f32x4){0.f, 0.f, 0.f, 0.f};
    float mrow[2][4], lrow[2][4];
#pragma unroll
    for (int i = 0; i < 2; i++)
#pragma unroll
        for (int r = 0; r < 4; r++) { mrow[i][r] = -__builtin_inff(); lrow[i][r] = 0.f; }

    int ntiles = qi / 2 + 1;
    for (int ti = w; ti < ntiles; ti += 4) {
        int sb = ti * 64;
        f32x4 s[2][4];
#pragma unroll
        for (int i = 0; i < 2; i++)
#pragma unroll
            for (int nf = 0; nf < 4; nf++) s[i][nf] = (f32x4){0.f, 0.f, 0.f, 0.f};
        {
            short8 kb[4][4];
#pragma unroll
            for (int nf = 0; nf < 4; nf++)
#pragma unroll
                for (int kf = 0; kf < 4; kf++)
                    kb[nf][kf] = *(const short8*)&Kb[(size_t)(sb + nf * 16 + lr) * 128 + kf * 32 + lg * 8];
#pragma unroll
            for (int kf = 0; kf < 4; kf++)
#pragma unroll
                for (int i = 0; i < 2; i++)
#pragma unroll
                    for (int nf = 0; nf < 4; nf++)
                        s[i][nf] = __builtin_amdgcn_mfma_f32_16x16x32_bf16(qf[i][kf], kb[nf][kf], s[i][nf], 0, 0, 0);
        }
        if (sb + 63 > qbase) {   // diagonal tile(s): causal mask
#pragma unroll
            for (int i = 0; i < 2; i++)
#pragma unroll
                for (int nf = 0; nf < 4; nf++)
#pragma unroll
                    for (int r = 0; r < 4; r++) {
                        int sg = sb + nf * 16 + lr;
                        int qg = qbase + i * 16 + (lg << 2) + r;
                        if (sg > qg) s[i][nf][r] = -__builtin_inff();
                    }
        }
        float alpha[2][4];
#pragma unroll
        for (int i = 0; i < 2; i++)
#pragma unroll
            for (int r = 0; r < 4; r++) {
                float pm = fmaxf(fmaxf(s[i][0][r], s[i][1][r]), fmaxf(s[i][2][r], s[i][3][r]));
                pm = fmaxf(pm, __shfl_xor(pm, 1));
                pm = fmaxf(pm, __shfl_xor(pm, 2));
                pm = fmaxf(pm, __shfl_xor(pm, 4));
                pm = fmaxf(pm, __shfl_xor(pm, 8));
                float mn = fmaxf(mrow[i][r], pm);
                alpha[i][r] = __expf(mrow[i][r] - mn);
                mrow[i][r] = mn;
            }
#pragma unroll
        for (int i = 0; i < 2; i++)
#pragma unroll
            for (int r = 0; r < 4; r++) {
                float rs = 0.f;
#pragma unroll
                for (int nf = 0; nf < 4; nf++) {
                    float p = __expf(s[i][nf][r] - mrow[i][r]);
                    s[i][nf][r] = p;
                    rs += p;
                }
                rs += __shfl_xor(rs, 1);
                rs += __shfl_xor(rs, 2);
                rs += __shfl_xor(rs, 4);
                rs += __shfl_xor(rs, 8);
                lrow[i][r] = lrow[i][r] * alpha[i][r] + rs;
            }
#pragma unroll
        for (int i = 0; i < 2; i++)
#pragma unroll
            for (int jn = 0; jn < 8; jn++)
#pragma unroll
                for (int r = 0; r < 4; r++) o[i][jn][r] *= alpha[i][r];
#pragma unroll
        for (int i = 0; i < 2; i++)
#pragma unroll
            for (int nf = 0; nf < 4; nf++)
#pragma unroll
                for (int r = 0; r < 4; r++) {
                    int row = i * 16 + (lg << 2) + r;
                    int cb2 = (nf * 16 + lr) * 2;
                    *(unsigned short*)(p_lds + swz128(row, cb2)) = f2bf(s[i][nf][r]);
                }
        asm volatile("s_waitcnt lgkmcnt(0)" ::: "memory");
        short8 pa[2][2];
#pragma unroll
        for (int i = 0; i < 2; i++)
#pragma unroll
            for (int kf = 0; kf < 2; kf++)
                pa[i][kf] = *(const short8*)(p_lds + swz128(i * 16 + lr, kf * 64 + lg * 16));
        short8 vb[8][2];
#pragma unroll
        for (int nf = 0; nf < 8; nf++)
#pragma unroll
            for (int kf = 0; kf < 2; kf++)
                vb[nf][kf] = *(const short8*)&Vt[(size_t)(nf * 16 + lr) * 2048 + sb + kf * 32 + lg * 8];
#pragma unroll
        for (int i = 0; i < 2; i++)
#pragma unroll
            for (int nf = 0; nf < 8; nf++)
#pragma unroll
                for (int kf = 0; kf < 2; kf++)
                    o[i][nf] = __builtin_amdgcn_mfma_f32_16x16x32_bf16(pa[i][kf], vb[nf][kf], o[i][nf], 0, 0, 0);
    }
#pragma unroll
    for (int i = 0; i < 2; i++)
#pragma unroll
        for (int r = 0; r < 4; r++) {
            int q = i * 16 + (lg << 2) + r;
            ml[w][0][q] = mrow[i][r];
            ml[w][1][q] = lrow[i][r];
        }
    asm volatile("s_waitcnt lgkmcnt(0)" ::: "memory");
#pragma unroll
    for (int i = 0; i < 2; i++)
#pragma unroll
        for (int jn = 0; jn < 8; jn++)
#pragma unroll
            for (int r = 0; r < 4; r++)
                o_lds[w][i * 16 + (lg << 2) + r][jn * 16 + lr] = o[i][jn][r];
    __syncthreads();
    int q = tid >> 3, h0 = (tid & 7) << 4;
    float mg = fmaxf(fmaxf(ml[0][0][q], ml[1][0][q]), fmaxf(ml[2][0][q], ml[3][0][q]));
    float scw[4], den = 0.f;
#pragma unroll
    for (int w4 = 0; w4 < 4; w4++) {
        scw[w4] = __expf(ml[w4][0][q] - mg);
        den += scw[w4] * ml[w4][1][q];
    }
    float inv = 1.0f / den;
    float* op = out + ((size_t)b * 2048 + qbase + q) * 128 + h0;
#pragma unroll
    for (int jj = 0; jj < 4; jj++) {
        f32x4 a4 = (f32x4){0.f, 0.f, 0.f, 0.f};
#pragma unroll
        for (int w4 = 0; w4 < 4; w4++) {
            f32x4 v = *(const f32x4*)&o_lds[w4][q][h0 + jj * 4];
            a4 += scw[w4] * v;
        }
        a4 *= inv;
        *(f32x4*)(op + jj * 4) = a4;
    }
}

extern "C" void kernel_launch(void* const* d_in, const int* in_sizes, int n_in,
                              void* d_out, int out_size, void* d_ws, size_t ws_size,
                              hipStream_t stream) {
    (void)in_sizes; (void)n_in; (void)out_size; (void)ws_size;
    const float* x  = (const float*)d_in[0];
    const float* Wq = (const float*)d_in[1];
    const float* bq = (const float*)d_in[2];
    const float* Wk = (const float*)d_in[3];
    const float* bk = (const float*)d_in[4];
    const float* Wv = (const float*)d_in[5];
    const float* bv = (const float*)d_in[6];
    unsigned short* ws = (unsigned short*)d_ws;
    float* out = (float*)d_out;

    wt_kernel<<<96, 256, 0, stream>>>(Wq, Wk, Wv, ws);
    qkv_kernel<<<768, 256, 0, stream>>>(x, bq, bk, bv, ws);
    attn_kernel<<<dim3(8, 64), 256, 0, stream>>>(ws, out);
}